// Round 6
// baseline (67.330 us; speedup 1.0000x reference)
//
#include <hip/hip_runtime.h>
#include <hip/hip_bf16.h>
#include <stdint.h>

typedef __bf16 bf16x8 __attribute__((ext_vector_type(8)));
typedef __bf16 bf16x4 __attribute__((ext_vector_type(4)));
typedef float  f32x4  __attribute__((ext_vector_type(4)));

#define NROWS 16384
#define NFEAT 26
#define VOCAB 100000

// lgkm-only barrier: syncs LDS but leaves global (vmcnt) prefetches in flight.
__device__ __forceinline__ void bar_lgkm() {
  asm volatile("s_waitcnt lgkmcnt(0)" ::: "memory");
  __builtin_amdgcn_s_barrier();
  asm volatile("" ::: "memory");
}

// ---------------- weight convert via LDS tile transpose ----------------
// W[K][N] fp32 (row-major) -> Wt[N][Kpad] bf16, zero-padded K->Kpad.
__device__ __forceinline__ void transpose_tile(const float* __restrict__ W,
                                               __bf16* __restrict__ Wt,
                                               int K, int N, int Kpad,
                                               int kt, int nt, int t) {
  __shared__ float tile[32][33];
  const int tx = t & 31, ty = t >> 5;           // 32 x 8
  const int k0 = kt * 32, n0 = nt * 32;
  #pragma unroll
  for (int j = 0; j < 4; ++j) {
    int k = k0 + ty + j * 8;
    tile[ty + j * 8][tx] = (k < K) ? W[(size_t)k * N + n0 + tx] : 0.f;
  }
  __syncthreads();
  #pragma unroll
  for (int j = 0; j < 4; ++j) {
    int n = n0 + ty + j * 8;
    Wt[(size_t)n * Kpad + k0 + tx] = (__bf16)tile[tx][ty + j * 8];
  }
}

__global__ __launch_bounds__(256) void k_convAll(
    const float* __restrict__ W1, const float* __restrict__ W2,
    const float* __restrict__ W3, const float* __restrict__ W4,
    __bf16* __restrict__ Wt1, __bf16* __restrict__ Wt2,
    __bf16* __restrict__ Wt3, __bf16* __restrict__ Wt4) {
  const int b = blockIdx.x, t = threadIdx.x;
  if (b < 224)       { int i = b;        transpose_tile(W1, Wt1, 429, 512, 448, i % 14, i / 14, t); }
  else if (b < 352)  { int i = b - 224;  transpose_tile(W2, Wt2, 512, 256, 512, i % 16, i / 16, t); }
  else if (b < 384)  { int i = b - 352;  transpose_tile(W3, Wt3, 256, 128, 256, i % 8,  i / 8,  t); }
  else               { int i = b - 384;  transpose_tile(W4, Wt4, 128,  64, 128, i % 4,  i / 4,  t); }
}

// ---------------- per-layer GEMM: A (LDS) x Wt[N][KP] bf16 (global/L2) -------------
// MT m-tiles (rows = MT*16). Wave w owns col-tiles {w + j*WS, j < NCT}.
template<int MT, int LDA, int KP, int N, int NCT, int WS, int LDO>
__device__ __forceinline__ void mlp_layer(const __bf16* __restrict__ Wt,
                                          const float* __restrict__ bias,
                                          const __bf16* Ain, __bf16* Aout,
                                          int w, int lane) {
  const int lrow = lane & 15;
  const int kg = (lane >> 4) * 8;

  f32x4 acc[NCT][MT];
  #pragma unroll
  for (int j = 0; j < NCT; ++j)
    #pragma unroll
    for (int m = 0; m < MT; ++m)
      #pragma unroll
      for (int i = 0; i < 4; ++i) acc[j][m][i] = 0.f;

  int col[NCT];
  #pragma unroll
  for (int j = 0; j < NCT; ++j) col[j] = (w + j * WS) * 16 + lrow;

  for (int k0 = 0; k0 < KP; k0 += 32) {
    bf16x8 af[MT];
    #pragma unroll
    for (int m = 0; m < MT; ++m)
      af[m] = *(const bf16x8*)(Ain + (m * 16 + lrow) * LDA + k0 + kg);
    #pragma unroll
    for (int j = 0; j < NCT; ++j) {
      bf16x8 bw = *(const bf16x8*)(Wt + (size_t)col[j] * KP + k0 + kg);
      #pragma unroll
      for (int m = 0; m < MT; ++m)
        acc[j][m] = __builtin_amdgcn_mfma_f32_16x16x32_bf16(af[m], bw, acc[j][m], 0, 0, 0);
    }
  }

  const int rbase = (lane >> 4) * 4;
  #pragma unroll
  for (int j = 0; j < NCT; ++j) {
    float bv = bias[col[j]];
    #pragma unroll
    for (int m = 0; m < MT; ++m)
      #pragma unroll
      for (int i = 0; i < 4; ++i) {
        float v = acc[j][m][i] + bv;
        v = fmaxf(v, 0.f);
        Aout[(m * 16 + rbase + i) * LDO + col[j]] = (__bf16)v;
      }
  }
}

// ---------------- fused: pipelined {gather || layer-1} + layers 2-5 + combine -------
// 32 rows/block, 512 threads (8 waves), 62.6 KB LDS -> 2 blocks/CU.
__global__ __launch_bounds__(512, 4) void k_fused(
    const float* __restrict__ x_int,   // [B,13]
    const int*   __restrict__ x_cat,   // [B,26]
    const float* __restrict__ emb,     // [26,V,16]
    const float* __restrict__ lin,     // [26,V]
    const float* __restrict__ W_num,   // [13]
    const float* __restrict__ b_num,   // [1]
    const float* __restrict__ bias0,   // [1]
    const __bf16* __restrict__ Wt1, const float* __restrict__ b1,
    const __bf16* __restrict__ Wt2, const float* __restrict__ b2,
    const __bf16* __restrict__ Wt3, const float* __restrict__ b3,
    const __bf16* __restrict__ Wt4, const float* __restrict__ b4,
    const float* __restrict__ W5, const float* __restrict__ b5,
    float* __restrict__ out) {
  // LDS (62592 B): A0 @0 : 32x456 bf16 (29184); A1 @29184 : 32x520 bf16 (33280,
  // s_idx aliases A1 head, dead before first A1 write); s_part @62464 : 32 f32.
  __shared__ __align__(16) char smem[62592];
  __bf16* A0 = (__bf16*)smem;
  __bf16* A1 = (__bf16*)(smem + 29184);
  int* s_idx = (int*)(smem + 29184);
  float* s_part = (float*)(smem + 62464);

  const int t = threadIdx.x;
  const int row0 = blockIdx.x * 32;
  const int w = t >> 6, lane = t & 63;
  const int lrow = lane & 15, kg = (lane >> 4) * 8;

  // ---- stage categorical indices ----
  #pragma unroll
  for (int i = t; i < 32 * NFEAT; i += 512) {
    int r = i / NFEAT, f = i - r * NFEAT;
    s_idx[i] = x_cat[(size_t)(row0 + r) * NFEAT + f];
  }
  bar_lgkm();

  const int r = t >> 4, d = t & 15;
  const int g = d >> 2, q = d & 3;   // feature-group (mod 4), dim-quad

  // ---- linear terms (issued early) ----
  float lin_s = 0.f;
  if (d < 13) {
    lin_s = lin[(size_t)d * VOCAB + s_idx[r * NFEAT + d]]
          + lin[(size_t)(d + 13) * VOCAB + s_idx[r * NFEAT + d + 13]]
          + x_int[(size_t)(row0 + r) * 13 + d] * W_num[d];
  }
  // x_int values for chunk-6 tail (cols 416..447), threads d=8..11
  float xv[4] = {0.f, 0.f, 0.f, 0.f};
  if (d >= 8 && d < 12) {
    int base = (d - 8) * 4;
    #pragma unroll
    for (int i = 0; i < 4; ++i)
      if (base + i < 13) xv[i] = x_int[(size_t)(row0 + r) * 13 + base + i];
  }

  // ---- layer-1 accumulators: NCT=4 col-tiles (stride 8), MT=2 m-tiles ----
  f32x4 acc[4][2];
  #pragma unroll
  for (int j = 0; j < 4; ++j)
    #pragma unroll
    for (int m = 0; m < 2; ++m)
      #pragma unroll
      for (int i = 0; i < 4; ++i) acc[j][m][i] = 0.f;
  int col1[4];
  #pragma unroll
  for (int j = 0; j < 4; ++j) col1[j] = (w + j * 8) * 16 + lrow;

  // ---- depth-2 pipelined gather || layer-1: 7 chunks of 64 K-cols ----
  float fsum[4] = {0.f,0.f,0.f,0.f}, fsq[4] = {0.f,0.f,0.f,0.f};
  f32x4 p0, p1;
  {
    int idx = s_idx[r * NFEAT + g];
    p0 = *(const f32x4*)(emb + ((size_t)g * VOCAB + idx) * 16 + q * 4);
  }
  {
    int idx = s_idx[r * NFEAT + 4 + g];
    p1 = *(const f32x4*)(emb + ((size_t)(4 + g) * VOCAB + idx) * 16 + q * 4);
  }

  #pragma unroll
  for (int c = 0; c < 7; ++c) {
    // issue chunk c+2's gather (2 in flight through this chunk's MFMA)
    f32x4 nxt;
    if (c < 5) {
      int fc = 4 * (c + 2) + g;
      if (fc < NFEAT) {
        int idx = s_idx[r * NFEAT + fc];
        nxt = *(const f32x4*)(emb + ((size_t)fc * VOCAB + idx) * 16 + q * 4);
      }
    }
    // consume chunk c -> LDS + FM partials
    const int colbase = c * 64 + g * 16 + q * 4;
    if (4 * c + g < NFEAT) {
      bf16x4 pk;
      #pragma unroll
      for (int i = 0; i < 4; ++i) {
        fsum[i] += p0[i]; fsq[i] += p0[i] * p0[i];
        pk[i] = (__bf16)p0[i];
      }
      *(bf16x4*)(A0 + r * 456 + colbase) = pk;
    } else {                       // c==6, g>=2: x_int + zero pad
      bf16x4 pk;
      #pragma unroll
      for (int i = 0; i < 4; ++i) pk[i] = (__bf16)xv[i];
      *(bf16x4*)(A0 + r * 456 + colbase) = pk;
    }
    bar_lgkm();   // prefetches (vmcnt) stay in flight
    // layer-1 MFMA over this chunk's 2 K-steps, Wt1 bf16 streamed from L2
    #pragma unroll
    for (int ks = 0; ks < 2; ++ks) {
      const int k0 = c * 64 + ks * 32;
      bf16x8 af[2];
      #pragma unroll
      for (int m = 0; m < 2; ++m)
        af[m] = *(const bf16x8*)(A0 + (m * 16 + lrow) * 456 + k0 + kg);
      #pragma unroll
      for (int j = 0; j < 4; ++j) {
        bf16x8 bw = *(const bf16x8*)(Wt1 + (size_t)col1[j] * 448 + k0 + kg);
        #pragma unroll
        for (int m = 0; m < 2; ++m)
          acc[j][m] = __builtin_amdgcn_mfma_f32_16x16x32_bf16(af[m], bw, acc[j][m], 0, 0, 0);
      }
    }
    p0 = p1; p1 = nxt;
  }

  // ---- layer-1 epilogue: bias + ReLU -> A1 (overwrites s_idx alias: safe now) ----
  {
    const int rbase = (lane >> 4) * 4;
    #pragma unroll
    for (int j = 0; j < 4; ++j) {
      float bv = b1[col1[j]];
      #pragma unroll
      for (int m = 0; m < 2; ++m)
        #pragma unroll
        for (int i = 0; i < 4; ++i) {
          float v = acc[j][m][i] + bv;
          v = fmaxf(v, 0.f);
          A1[(m * 16 + rbase + i) * 520 + col1[j]] = (__bf16)v;
        }
    }
  }

  // ---- FM + linear combine -> s_part ----
  {
    #pragma unroll
    for (int i = 0; i < 4; ++i) {
      fsum[i] += __shfl_xor(fsum[i], 4); fsq[i] += __shfl_xor(fsq[i], 4);
      fsum[i] += __shfl_xor(fsum[i], 8); fsq[i] += __shfl_xor(fsq[i], 8);
    }
    float fmq = 0.f;
    #pragma unroll
    for (int i = 0; i < 4; ++i) fmq += fsum[i] * fsum[i] - fsq[i];
    fmq += __shfl_xor(fmq, 1);
    fmq += __shfl_xor(fmq, 2);
    float linred = lin_s;
    #pragma unroll
    for (int off = 1; off < 16; off <<= 1) linred += __shfl_xor(linred, off, 16);
    if (d == 0) s_part[r] = 0.5f * fmq + linred + bias0[0] + b_num[0];
  }
  bar_lgkm();

  // ---- layers 2-4 (bf16 weights, one dwordx4 per fragment) ----
  mlp_layer<2, 520, 512, 256, 2, 8, 264>(Wt2, b2, A1, A0, w, lane);
  bar_lgkm();
  mlp_layer<2, 264, 256, 128, 1, 8, 136>(Wt3, b3, A0, A1, w, lane);
  bar_lgkm();
  if (w < 4) mlp_layer<2, 136, 128, 64, 1, 4, 72>(Wt4, b4, A1, A0, w, lane);
  bar_lgkm();

  // ---- final 64->1 dot + combine ----
  {
    const int rr = t >> 4, gg = t & 15;
    float s = 0.f;
    #pragma unroll
    for (int i = 0; i < 4; ++i)
      s += (float)A0[rr * 72 + gg * 4 + i] * W5[gg * 4 + i];
    #pragma unroll
    for (int off = 1; off < 16; off <<= 1) s += __shfl_xor(s, off, 16);
    if (gg == 0) out[row0 + rr] = s + b5[0] + s_part[rr];
  }
}

extern "C" void kernel_launch(void* const* d_in, const int* in_sizes, int n_in,
                              void* d_out, int out_size, void* d_ws, size_t ws_size,
                              hipStream_t stream) {
  const float* x_int = (const float*)d_in[0];
  const int*   x_cat = (const int*)d_in[1];
  const float* emb   = (const float*)d_in[2];
  const float* lin   = (const float*)d_in[3];
  const float* W_num = (const float*)d_in[4];
  const float* b_num = (const float*)d_in[5];
  const float* bias  = (const float*)d_in[6];
  const float* W1 = (const float*)d_in[7];  const float* b1 = (const float*)d_in[8];
  const float* W2 = (const float*)d_in[9];  const float* b2 = (const float*)d_in[10];
  const float* W3 = (const float*)d_in[11]; const float* b3 = (const float*)d_in[12];
  const float* W4 = (const float*)d_in[13]; const float* b4 = (const float*)d_in[14];
  const float* W5 = (const float*)d_in[15]; const float* b5 = (const float*)d_in[16];
  float* out = (float*)d_out;

  char* ws = (char*)d_ws;
  __bf16* Wt1 = (__bf16*)(ws);            // [512][448] = 458752 B
  __bf16* Wt2 = (__bf16*)(ws + 458752);   // [256][512] = 262144 B
  __bf16* Wt3 = (__bf16*)(ws + 720896);   // [128][256] =  65536 B
  __bf16* Wt4 = (__bf16*)(ws + 786432);   // [64][128]  =  16384 B

  k_convAll<<<392, 256, 0, stream>>>(W1, W2, W3, W4, Wt1, Wt2, Wt3, Wt4);

  k_fused<<<NROWS / 32, 512, 0, stream>>>(x_int, x_cat, emb, lin, W_num, b_num, bias,
                                          Wt1, b1, Wt2, b2, Wt3, b3, Wt4, b4, W5, b5,
                                          out);
}

// Round 7
// 52.522 us; speedup vs baseline: 1.2819x; 1.2819x over previous
//
#include <hip/hip_runtime.h>
#include <hip/hip_bf16.h>
#include <stdint.h>

typedef __bf16 bf16x8 __attribute__((ext_vector_type(8)));
typedef __bf16 bf16x4 __attribute__((ext_vector_type(4)));
typedef float  f32x4  __attribute__((ext_vector_type(4)));

#define NROWS 16384
#define NFEAT 26
#define VOCAB 100000

// lgkm-only barrier: syncs LDS but leaves global (vmcnt) prefetches in flight.
__device__ __forceinline__ void bar_lgkm() {
  asm volatile("s_waitcnt lgkmcnt(0)" ::: "memory");
  __builtin_amdgcn_s_barrier();
  asm volatile("" ::: "memory");
}

// ---------------- weight convert via LDS tile transpose ----------------
// W[K][N] fp32 (row-major) -> Wt[N][Kpad] bf16, zero-padded K->Kpad.
__device__ __forceinline__ void transpose_tile(const float* __restrict__ W,
                                               __bf16* __restrict__ Wt,
                                               int K, int N, int Kpad,
                                               int kt, int nt, int t) {
  __shared__ float tile[32][33];
  const int tx = t & 31, ty = t >> 5;           // 32 x 8
  const int k0 = kt * 32, n0 = nt * 32;
  #pragma unroll
  for (int j = 0; j < 4; ++j) {
    int k = k0 + ty + j * 8;
    tile[ty + j * 8][tx] = (k < K) ? W[(size_t)k * N + n0 + tx] : 0.f;
  }
  __syncthreads();
  #pragma unroll
  for (int j = 0; j < 4; ++j) {
    int n = n0 + ty + j * 8;
    Wt[(size_t)n * Kpad + k0 + tx] = (__bf16)tile[tx][ty + j * 8];
  }
}

__global__ __launch_bounds__(256) void k_convAll(
    const float* __restrict__ W1, const float* __restrict__ W2,
    const float* __restrict__ W3, const float* __restrict__ W4,
    __bf16* __restrict__ Wt1, __bf16* __restrict__ Wt2,
    __bf16* __restrict__ Wt3, __bf16* __restrict__ Wt4) {
  const int b = blockIdx.x, t = threadIdx.x;
  if (b < 224)       { int i = b;        transpose_tile(W1, Wt1, 429, 512, 448, i % 14, i / 14, t); }
  else if (b < 352)  { int i = b - 224;  transpose_tile(W2, Wt2, 512, 256, 512, i % 16, i / 16, t); }
  else if (b < 384)  { int i = b - 352;  transpose_tile(W3, Wt3, 256, 128, 256, i % 8,  i / 8,  t); }
  else               { int i = b - 384;  transpose_tile(W4, Wt4, 128,  64, 128, i % 4,  i / 4,  t); }
}

// ---------------- per-layer GEMM: A (LDS) x Wt[N][KP] bf16 (global/L2) -------------
// MT m-tiles (rows = MT*16). Wave w owns col-tiles {w + j*WS, j < NCT}.
template<int MT, int LDA, int KP, int N, int NCT, int WS, int LDO>
__device__ __forceinline__ void mlp_layer(const __bf16* __restrict__ Wt,
                                          const float* __restrict__ bias,
                                          const __bf16* Ain, __bf16* Aout,
                                          int w, int lane) {
  const int lrow = lane & 15;
  const int kg = (lane >> 4) * 8;

  f32x4 acc[NCT][MT];
  #pragma unroll
  for (int j = 0; j < NCT; ++j)
    #pragma unroll
    for (int m = 0; m < MT; ++m)
      #pragma unroll
      for (int i = 0; i < 4; ++i) acc[j][m][i] = 0.f;

  int col[NCT];
  #pragma unroll
  for (int j = 0; j < NCT; ++j) col[j] = (w + j * WS) * 16 + lrow;

  for (int k0 = 0; k0 < KP; k0 += 32) {
    bf16x8 af[MT];
    #pragma unroll
    for (int m = 0; m < MT; ++m)
      af[m] = *(const bf16x8*)(Ain + (m * 16 + lrow) * LDA + k0 + kg);
    #pragma unroll
    for (int j = 0; j < NCT; ++j) {
      bf16x8 bw = *(const bf16x8*)(Wt + (size_t)col[j] * KP + k0 + kg);
      #pragma unroll
      for (int m = 0; m < MT; ++m)
        acc[j][m] = __builtin_amdgcn_mfma_f32_16x16x32_bf16(af[m], bw, acc[j][m], 0, 0, 0);
    }
  }

  const int rbase = (lane >> 4) * 4;
  #pragma unroll
  for (int j = 0; j < NCT; ++j) {
    float bv = bias[col[j]];
    #pragma unroll
    for (int m = 0; m < MT; ++m)
      #pragma unroll
      for (int i = 0; i < 4; ++i) {
        float v = acc[j][m][i] + bv;
        v = fmaxf(v, 0.f);
        Aout[(m * 16 + rbase + i) * LDO + col[j]] = (__bf16)v;
      }
  }
}

// ---------------- fused: pipelined {gather || layer-1} + layers 2-5 + combine -------
// 64 rows/block, 1024 threads (16 waves), 1 block/CU (R5 structure).
__global__ __launch_bounds__(1024) void k_fused(
    const float* __restrict__ x_int,   // [B,13]
    const int*   __restrict__ x_cat,   // [B,26]
    const float* __restrict__ emb,     // [26,V,16]
    const float* __restrict__ lin,     // [26,V]
    const float* __restrict__ W_num,   // [13]
    const float* __restrict__ b_num,   // [1]
    const float* __restrict__ bias0,   // [1]
    const __bf16* __restrict__ Wt1, const float* __restrict__ b1,
    const __bf16* __restrict__ Wt2, const float* __restrict__ b2,
    const __bf16* __restrict__ Wt3, const float* __restrict__ b3,
    const __bf16* __restrict__ Wt4, const float* __restrict__ b4,
    const float* __restrict__ W5, const float* __restrict__ b5,
    float* __restrict__ out) {
  // LDS (125184 B): A0 @0 : 64x456 bf16; A1 @58368 : 64x520 bf16 (s_idx aliases
  // A1 head, dead before first A1 write); s_part @124928 : 64 f32.
  __shared__ __align__(16) char smem[125184];
  __bf16* A0 = (__bf16*)smem;
  __bf16* A1 = (__bf16*)(smem + 58368);
  int* s_idx = (int*)(smem + 58368);
  float* s_part = (float*)(smem + 124928);

  const int t = threadIdx.x;
  const int row0 = blockIdx.x * 64;
  const int w = t >> 6, lane = t & 63;
  const int lrow = lane & 15, kg = (lane >> 4) * 8;

  // ---- stage categorical indices (nontemporal: single-use stream) ----
  for (int i = t; i < 64 * NFEAT; i += 1024) {
    int r = i / NFEAT, f = i - r * NFEAT;
    s_idx[i] = __builtin_nontemporal_load(x_cat + (size_t)(row0 + r) * NFEAT + f);
  }
  __syncthreads();

  const int r = t >> 4, d = t & 15;
  const int g = d >> 2, q = d & 3;   // feature-group (mod 4), dim-quad

  // ---- linear terms (issued early, consumed after layer-1 loop) ----
  float lin_s = 0.f;
  if (d < 13) {
    lin_s = __builtin_nontemporal_load(lin + (size_t)d * VOCAB + s_idx[r * NFEAT + d])
          + __builtin_nontemporal_load(lin + (size_t)(d + 13) * VOCAB + s_idx[r * NFEAT + d + 13])
          + x_int[(size_t)(row0 + r) * 13 + d] * W_num[d];
  }
  // x_int values for chunk-6 LDS tail (cols 416..447), threads d=8..11
  float xv[4] = {0.f, 0.f, 0.f, 0.f};
  if (d >= 8 && d < 12) {
    int base = (d - 8) * 4;
    #pragma unroll
    for (int i = 0; i < 4; ++i)
      if (base + i < 13) xv[i] = x_int[(size_t)(row0 + r) * 13 + base + i];
  }

  // ---- layer-1 accumulators (NCT=2, wave-stride 16) ----
  f32x4 acc[2][4];
  #pragma unroll
  for (int j = 0; j < 2; ++j)
    #pragma unroll
    for (int m = 0; m < 4; ++m)
      #pragma unroll
      for (int i = 0; i < 4; ++i) acc[j][m][i] = 0.f;
  const int colL1[2] = { w * 16 + lrow, (w + 16) * 16 + lrow };

  // ---- pipelined gather || layer-1: 7 chunks of 64 K-cols (4 features) ----
  float fsum[4] = {0.f,0.f,0.f,0.f}, fsq[4] = {0.f,0.f,0.f,0.f};
  f32x4 cur;
  {
    int idx = s_idx[r * NFEAT + g];
    cur = __builtin_nontemporal_load((const f32x4*)(emb + ((size_t)g * VOCAB + idx) * 16 + q * 4));
  }

  #pragma unroll
  for (int c = 0; c < 7; ++c) {
    // issue next chunk's gather (overlaps this chunk's MFMA below)
    f32x4 nxt;
    if (c < 6) {
      int fc = 4 * (c + 1) + g;
      if (fc < NFEAT) {
        int idx = s_idx[r * NFEAT + fc];
        nxt = __builtin_nontemporal_load((const f32x4*)(emb + ((size_t)fc * VOCAB + idx) * 16 + q * 4));
      }
    }
    // consume current chunk -> LDS + FM partials
    const int colbase = c * 64 + g * 16 + q * 4;
    if (4 * c + g < NFEAT) {
      bf16x4 pk;
      #pragma unroll
      for (int i = 0; i < 4; ++i) {
        fsum[i] += cur[i]; fsq[i] += cur[i] * cur[i];
        pk[i] = (__bf16)cur[i];
      }
      *(bf16x4*)(A0 + r * 456 + colbase) = pk;
    } else {                       // c==6, g>=2: x_int + zero pad
      bf16x4 pk;
      #pragma unroll
      for (int i = 0; i < 4; ++i) pk[i] = (__bf16)xv[i];
      *(bf16x4*)(A0 + r * 456 + colbase) = pk;
    }
    bar_lgkm();   // prefetches (vmcnt) stay in flight
    // layer-1 MFMA over this chunk's 2 K-steps, Wt1 bf16 streamed from L2/L3
    #pragma unroll
    for (int ks = 0; ks < 2; ++ks) {
      const int k0 = c * 64 + ks * 32;
      bf16x8 af[4];
      #pragma unroll
      for (int m = 0; m < 4; ++m)
        af[m] = *(const bf16x8*)(A0 + (m * 16 + lrow) * 456 + k0 + kg);
      #pragma unroll
      for (int j = 0; j < 2; ++j) {
        bf16x8 bw = *(const bf16x8*)(Wt1 + (size_t)colL1[j] * 448 + k0 + kg);
        #pragma unroll
        for (int m = 0; m < 4; ++m)
          acc[j][m] = __builtin_amdgcn_mfma_f32_16x16x32_bf16(af[m], bw, acc[j][m], 0, 0, 0);
      }
    }
    cur = nxt;
  }

  // ---- layer-1 epilogue: bias + ReLU -> A1 (overwrites s_idx alias: safe now) ----
  {
    const int rbase = (lane >> 4) * 4;
    #pragma unroll
    for (int j = 0; j < 2; ++j) {
      float bv = b1[colL1[j]];
      #pragma unroll
      for (int m = 0; m < 4; ++m)
        #pragma unroll
        for (int i = 0; i < 4; ++i) {
          float v = acc[j][m][i] + bv;
          v = fmaxf(v, 0.f);
          A1[(m * 16 + rbase + i) * 520 + colL1[j]] = (__bf16)v;
        }
    }
  }

  // ---- FM + linear combine -> s_part ----
  {
    #pragma unroll
    for (int i = 0; i < 4; ++i) {
      fsum[i] += __shfl_xor(fsum[i], 4); fsq[i] += __shfl_xor(fsq[i], 4);
      fsum[i] += __shfl_xor(fsum[i], 8); fsq[i] += __shfl_xor(fsq[i], 8);
    }
    float fmq = 0.f;
    #pragma unroll
    for (int i = 0; i < 4; ++i) fmq += fsum[i] * fsum[i] - fsq[i];
    fmq += __shfl_xor(fmq, 1);
    fmq += __shfl_xor(fmq, 2);     // full FM, replicated over d
    float linred = lin_s;
    #pragma unroll
    for (int off = 1; off < 16; off <<= 1) linred += __shfl_xor(linred, off, 16);
    if (d == 0) s_part[r] = 0.5f * fmq + linred + bias0[0] + b_num[0];
  }
  __syncthreads();

  // ---- layers 2-4 (bf16 weights, one dwordx4 per fragment) ----
  mlp_layer<4, 520, 512, 256, 1, 16, 264>(Wt2, b2, A1, A0, w, lane);
  __syncthreads();
  if (w < 8) mlp_layer<4, 264, 256, 128, 1, 8, 136>(Wt3, b3, A0, A1, w, lane);
  __syncthreads();
  if (w < 4) mlp_layer<4, 136, 128, 64, 1, 4, 72>(Wt4, b4, A1, A0, w, lane);
  __syncthreads();

  // ---- final 64->1 dot + combine ----
  {
    const int rr = t >> 4, gg = t & 15;
    float s = 0.f;
    #pragma unroll
    for (int i = 0; i < 4; ++i)
      s += (float)A0[rr * 72 + gg * 4 + i] * W5[gg * 4 + i];
    #pragma unroll
    for (int off = 1; off < 16; off <<= 1) s += __shfl_xor(s, off, 16);
    if (gg == 0) out[row0 + rr] = s + b5[0] + s_part[rr];
  }
}

extern "C" void kernel_launch(void* const* d_in, const int* in_sizes, int n_in,
                              void* d_out, int out_size, void* d_ws, size_t ws_size,
                              hipStream_t stream) {
  const float* x_int = (const float*)d_in[0];
  const int*   x_cat = (const int*)d_in[1];
  const float* emb   = (const float*)d_in[2];
  const float* lin   = (const float*)d_in[3];
  const float* W_num = (const float*)d_in[4];
  const float* b_num = (const float*)d_in[5];
  const float* bias  = (const float*)d_in[6];
  const float* W1 = (const float*)d_in[7];  const float* b1 = (const float*)d_in[8];
  const float* W2 = (const float*)d_in[9];  const float* b2 = (const float*)d_in[10];
  const float* W3 = (const float*)d_in[11]; const float* b3 = (const float*)d_in[12];
  const float* W4 = (const float*)d_in[13]; const float* b4 = (const float*)d_in[14];
  const float* W5 = (const float*)d_in[15]; const float* b5 = (const float*)d_in[16];
  float* out = (float*)d_out;

  char* ws = (char*)d_ws;
  __bf16* Wt1 = (__bf16*)(ws);            // [512][448] = 458752 B
  __bf16* Wt2 = (__bf16*)(ws + 458752);   // [256][512] = 262144 B
  __bf16* Wt3 = (__bf16*)(ws + 720896);   // [128][256] =  65536 B
  __bf16* Wt4 = (__bf16*)(ws + 786432);   // [64][128]  =  16384 B

  k_convAll<<<392, 256, 0, stream>>>(W1, W2, W3, W4, Wt1, Wt2, Wt3, Wt4);

  k_fused<<<NROWS / 64, 1024, 0, stream>>>(x_int, x_cat, emb, lin, W_num, b_num, bias,
                                           Wt1, b1, Wt2, b2, Wt3, b3, Wt4, b4, W5, b5,
                                           out);
}

// Round 8
// 49.664 us; speedup vs baseline: 1.3557x; 1.0576x over previous
//
#include <hip/hip_runtime.h>
#include <hip/hip_bf16.h>
#include <stdint.h>

typedef __bf16 bf16x8 __attribute__((ext_vector_type(8)));
typedef __bf16 bf16x4 __attribute__((ext_vector_type(4)));
typedef float  f32x4  __attribute__((ext_vector_type(4)));

#define NROWS 16384
#define NFEAT 26
#define VOCAB 100000

// lgkm-only barrier: syncs LDS but leaves global (vmcnt) prefetches in flight.
__device__ __forceinline__ void bar_lgkm() {
  asm volatile("s_waitcnt lgkmcnt(0)" ::: "memory");
  __builtin_amdgcn_s_barrier();
  asm volatile("" ::: "memory");
}

// ---------------- per-layer GEMM (layers 2-4): A (LDS) x W[KREAL][N] fp32 ----------
template<int KPAD, int KREAL, int N, int NCT, int WS>
__device__ __forceinline__ void mlp_layer(const float* __restrict__ W,
                                          const float* __restrict__ bias,
                                          const __bf16* Ain, __bf16* Aout,
                                          int w, int lane) {
  constexpr int LDA = KPAD + 8, LDO = N + 8;
  const int lrow = lane & 15;
  const int kg = (lane >> 4) * 8;

  f32x4 acc[NCT][4];
  #pragma unroll
  for (int j = 0; j < NCT; ++j)
    #pragma unroll
    for (int m = 0; m < 4; ++m)
      #pragma unroll
      for (int i = 0; i < 4; ++i) acc[j][m][i] = 0.f;

  int col[NCT];
  #pragma unroll
  for (int j = 0; j < NCT; ++j) col[j] = (w + j * WS) * 16 + lrow;

  for (int k0 = 0; k0 < KREAL; k0 += 32) {
    bf16x8 af[4];
    #pragma unroll
    for (int m = 0; m < 4; ++m)
      af[m] = *(const bf16x8*)(Ain + (m * 16 + lrow) * LDA + k0 + kg);
    #pragma unroll
    for (int j = 0; j < NCT; ++j) {
      bf16x8 bw;
      #pragma unroll
      for (int i = 0; i < 8; ++i)
        bw[i] = (__bf16)W[(size_t)(k0 + kg + i) * N + col[j]];
      #pragma unroll
      for (int m = 0; m < 4; ++m)
        acc[j][m] = __builtin_amdgcn_mfma_f32_16x16x32_bf16(af[m], bw, acc[j][m], 0, 0, 0);
    }
  }

  const int rbase = (lane >> 4) * 4;
  #pragma unroll
  for (int j = 0; j < NCT; ++j) {
    float bv = bias[col[j]];
    #pragma unroll
    for (int m = 0; m < 4; ++m)
      #pragma unroll
      for (int i = 0; i < 4; ++i) {
        float v = acc[j][m][i] + bv;
        v = fmaxf(v, 0.f);
        Aout[(m * 16 + rbase + i) * LDO + col[j]] = (__bf16)v;
      }
  }
}

// ---------------- fused: deep-prefetch gather + pipelined layer-1 + layers 2-5 ------
__global__ __launch_bounds__(1024) void k_fused(
    const float* __restrict__ x_int,   // [B,13]
    const int*   __restrict__ x_cat,   // [B,26]
    const float* __restrict__ emb,     // [26,V,16]
    const float* __restrict__ lin,     // [26,V]
    const float* __restrict__ W_num,   // [13]
    const float* __restrict__ b_num,   // [1]
    const float* __restrict__ bias0,   // [1]
    const float* __restrict__ W1, const float* __restrict__ b1,
    const float* __restrict__ W2, const float* __restrict__ b2,
    const float* __restrict__ W3, const float* __restrict__ b3,
    const float* __restrict__ W4, const float* __restrict__ b4,
    const float* __restrict__ W5, const float* __restrict__ b5,
    float* __restrict__ out) {
  // LDS (125184 B): A0 @0 : 64x456 bf16; A1 @58368 : 64x520 bf16 (s_idx aliases
  // A1 head, dead before first A1 write); s_part @124928 : 64 f32.
  __shared__ __align__(16) char smem[125184];
  __bf16* A0 = (__bf16*)smem;
  __bf16* A1 = (__bf16*)(smem + 58368);
  int* s_idx = (int*)(smem + 58368);
  float* s_part = (float*)(smem + 124928);

  const int t = threadIdx.x;
  const int row0 = blockIdx.x * 64;
  const int w = t >> 6, lane = t & 63;
  const int lrow = lane & 15, kg = (lane >> 4) * 8;

  // ---- stage categorical indices ----
  for (int i = t; i < 64 * NFEAT; i += 1024) {
    int r = i / NFEAT, f = i - r * NFEAT;
    s_idx[i] = x_cat[(size_t)(row0 + r) * NFEAT + f];
  }
  __syncthreads();

  const int r = t >> 4, d = t & 15;
  const int g = d >> 2, q = d & 3;   // feature-group (mod 4), dim-quad

  // ---- linear terms (longest-latency single-use loads: issue first) ----
  float lin_s = 0.f;
  if (d < 13) {
    lin_s = lin[(size_t)d * VOCAB + s_idx[r * NFEAT + d]]
          + lin[(size_t)(d + 13) * VOCAB + s_idx[r * NFEAT + d + 13]]
          + x_int[(size_t)(row0 + r) * 13 + d] * W_num[d];
  }
  // x_int values for chunk-6 LDS tail (cols 416..447), threads d=8..11
  float xv[4] = {0.f, 0.f, 0.f, 0.f};
  if (d >= 8 && d < 12) {
    int base = (d - 8) * 4;
    #pragma unroll
    for (int i = 0; i < 4; ++i)
      if (base + i < 13) xv[i] = x_int[(size_t)(row0 + r) * 13 + base + i];
  }

  // ---- deep prefetch: ALL 7 scattered emb lines per thread issued up front ----
  f32x4 pf[7];
  #pragma unroll
  for (int c = 0; c < 7; ++c) {
    int fc = 4 * c + g;
    if (fc < NFEAT) {
      int idx = s_idx[r * NFEAT + fc];
      pf[c] = *(const f32x4*)(emb + ((size_t)fc * VOCAB + idx) * 16 + q * 4);
    }
  }

  // ---- layer-1 accumulators (NCT=2, wave-stride 16) ----
  f32x4 acc[2][4];
  #pragma unroll
  for (int j = 0; j < 2; ++j)
    #pragma unroll
    for (int m = 0; m < 4; ++m)
      #pragma unroll
      for (int i = 0; i < 4; ++i) acc[j][m][i] = 0.f;
  const int colL1[2] = { w * 16 + lrow, (w + 16) * 16 + lrow };

  // ---- 7 chunks: consume pf[c] -> LDS, barrier, layer-1 MFMA on the chunk ----
  float fsum[4] = {0.f,0.f,0.f,0.f}, fsq[4] = {0.f,0.f,0.f,0.f};
  #pragma unroll
  for (int c = 0; c < 7; ++c) {
    const int colbase = c * 64 + g * 16 + q * 4;
    if (4 * c + g < NFEAT) {
      bf16x4 pk;
      #pragma unroll
      for (int i = 0; i < 4; ++i) {
        fsum[i] += pf[c][i]; fsq[i] += pf[c][i] * pf[c][i];
        pk[i] = (__bf16)pf[c][i];
      }
      *(bf16x4*)(A0 + r * 456 + colbase) = pk;
    } else {                       // c==6, g>=2: x_int + zero pad
      bf16x4 pk;
      #pragma unroll
      for (int i = 0; i < 4; ++i) pk[i] = (__bf16)xv[i];
      *(bf16x4*)(A0 + r * 456 + colbase) = pk;
    }
    bar_lgkm();   // remaining prefetches (vmcnt) stay in flight
    // layer-1 MFMA over this chunk's 2 K-steps, W1 fp32 streamed from L2
    #pragma unroll
    for (int ks = 0; ks < 2; ++ks) {
      const int k0 = c * 64 + ks * 32;
      bf16x8 af[4];
      #pragma unroll
      for (int m = 0; m < 4; ++m)
        af[m] = *(const bf16x8*)(A0 + (m * 16 + lrow) * 456 + k0 + kg);
      #pragma unroll
      for (int j = 0; j < 2; ++j) {
        bf16x8 bw;
        #pragma unroll
        for (int i = 0; i < 8; ++i) {
          int k = k0 + kg + i;
          float v;
          if (c < 6) v = W1[(size_t)k * 512 + colL1[j]];
          else       v = (k < 429) ? W1[(size_t)k * 512 + colL1[j]] : 0.f;
          bw[i] = (__bf16)v;
        }
        #pragma unroll
        for (int m = 0; m < 4; ++m)
          acc[j][m] = __builtin_amdgcn_mfma_f32_16x16x32_bf16(af[m], bw, acc[j][m], 0, 0, 0);
      }
    }
  }

  // ---- layer-1 epilogue: bias + ReLU -> A1 (overwrites s_idx alias: safe now) ----
  {
    const int rbase = (lane >> 4) * 4;
    #pragma unroll
    for (int j = 0; j < 2; ++j) {
      float bv = b1[colL1[j]];
      #pragma unroll
      for (int m = 0; m < 4; ++m)
        #pragma unroll
        for (int i = 0; i < 4; ++i) {
          float v = acc[j][m][i] + bv;
          v = fmaxf(v, 0.f);
          A1[(m * 16 + rbase + i) * 520 + colL1[j]] = (__bf16)v;
        }
    }
  }

  // ---- FM + linear combine -> s_part ----
  {
    #pragma unroll
    for (int i = 0; i < 4; ++i) {
      fsum[i] += __shfl_xor(fsum[i], 4); fsq[i] += __shfl_xor(fsq[i], 4);
      fsum[i] += __shfl_xor(fsum[i], 8); fsq[i] += __shfl_xor(fsq[i], 8);
    }
    float fmq = 0.f;
    #pragma unroll
    for (int i = 0; i < 4; ++i) fmq += fsum[i] * fsum[i] - fsq[i];
    fmq += __shfl_xor(fmq, 1);
    fmq += __shfl_xor(fmq, 2);     // full FM, replicated over d
    float linred = lin_s;
    #pragma unroll
    for (int off = 1; off < 16; off <<= 1) linred += __shfl_xor(linred, off, 16);
    if (d == 0) s_part[r] = 0.5f * fmq + linred + bias0[0] + b_num[0];
  }
  __syncthreads();

  // ---- layers 2-4 (fp32 weights direct from read-only inputs) ----
  mlp_layer<512, 512, 256, 1, 16>(W2, b2, A1, A0, w, lane);
  __syncthreads();
  if (w < 8) mlp_layer<256, 256, 128, 1, 8>(W3, b3, A0, A1, w, lane);
  __syncthreads();
  if (w < 4) mlp_layer<128, 128, 64, 1, 4>(W4, b4, A1, A0, w, lane);
  __syncthreads();

  // ---- final 64->1 dot + combine ----
  {
    const int rr = t >> 4, gg = t & 15;
    float s = 0.f;
    #pragma unroll
    for (int i = 0; i < 4; ++i)
      s += (float)A0[rr * 72 + gg * 4 + i] * W5[gg * 4 + i];
    #pragma unroll
    for (int off = 1; off < 16; off <<= 1) s += __shfl_xor(s, off, 16);
    if (gg == 0) out[row0 + rr] = s + b5[0] + s_part[rr];
  }
}

extern "C" void kernel_launch(void* const* d_in, const int* in_sizes, int n_in,
                              void* d_out, int out_size, void* d_ws, size_t ws_size,
                              hipStream_t stream) {
  const float* x_int = (const float*)d_in[0];
  const int*   x_cat = (const int*)d_in[1];
  const float* emb   = (const float*)d_in[2];
  const float* lin   = (const float*)d_in[3];
  const float* W_num = (const float*)d_in[4];
  const float* b_num = (const float*)d_in[5];
  const float* bias  = (const float*)d_in[6];
  const float* W1 = (const float*)d_in[7];  const float* b1 = (const float*)d_in[8];
  const float* W2 = (const float*)d_in[9];  const float* b2 = (const float*)d_in[10];
  const float* W3 = (const float*)d_in[11]; const float* b3 = (const float*)d_in[12];
  const float* W4 = (const float*)d_in[13]; const float* b4 = (const float*)d_in[14];
  const float* W5 = (const float*)d_in[15]; const float* b5 = (const float*)d_in[16];
  float* out = (float*)d_out;

  k_fused<<<NROWS / 64, 1024, 0, stream>>>(x_int, x_cat, emb, lin, W_num, b_num, bias,
                                           W1, b1, W2, b2, W3, b3, W4, b4, W5, b5,
                                           out);
}

// Round 9
// 49.632 us; speedup vs baseline: 1.3566x; 1.0006x over previous
//
#include <hip/hip_runtime.h>
#include <hip/hip_bf16.h>
#include <stdint.h>

typedef __bf16 bf16x8 __attribute__((ext_vector_type(8)));
typedef __bf16 bf16x4 __attribute__((ext_vector_type(4)));
typedef float  f32x4  __attribute__((ext_vector_type(4)));

#define NROWS 16384
#define NFEAT 26
#define VOCAB 100000

// lgkm-only barrier: syncs LDS but leaves global (vmcnt) prefetches in flight.
__device__ __forceinline__ void bar_lgkm() {
  asm volatile("s_waitcnt lgkmcnt(0)" ::: "memory");
  __builtin_amdgcn_s_barrier();
  asm volatile("" ::: "memory");
}

// ---------------- weight convert via LDS tile transpose ----------------
// W[K][N] fp32 (row-major) -> Wt[N][Kpad] bf16, zero-padded K->Kpad.
__device__ __forceinline__ void transpose_tile(const float* __restrict__ W,
                                               __bf16* __restrict__ Wt,
                                               int K, int N, int Kpad,
                                               int kt, int nt, int t) {
  __shared__ float tile[32][33];
  const int tx = t & 31, ty = t >> 5;           // 32 x 8
  const int k0 = kt * 32, n0 = nt * 32;
  #pragma unroll
  for (int j = 0; j < 4; ++j) {
    int k = k0 + ty + j * 8;
    tile[ty + j * 8][tx] = (k < K) ? W[(size_t)k * N + n0 + tx] : 0.f;
  }
  __syncthreads();
  #pragma unroll
  for (int j = 0; j < 4; ++j) {
    int n = n0 + ty + j * 8;
    Wt[(size_t)n * Kpad + k0 + tx] = (__bf16)tile[tx][ty + j * 8];
  }
}

__global__ __launch_bounds__(256) void k_convAll(
    const float* __restrict__ W1, const float* __restrict__ W2,
    const float* __restrict__ W3, const float* __restrict__ W4,
    __bf16* __restrict__ Wt1, __bf16* __restrict__ Wt2,
    __bf16* __restrict__ Wt3, __bf16* __restrict__ Wt4) {
  const int b = blockIdx.x, t = threadIdx.x;
  if (b < 224)       { int i = b;        transpose_tile(W1, Wt1, 429, 512, 448, i % 14, i / 14, t); }
  else if (b < 352)  { int i = b - 224;  transpose_tile(W2, Wt2, 512, 256, 512, i % 16, i / 16, t); }
  else if (b < 384)  { int i = b - 352;  transpose_tile(W3, Wt3, 256, 128, 256, i % 8,  i / 8,  t); }
  else               { int i = b - 384;  transpose_tile(W4, Wt4, 128,  64, 128, i % 4,  i / 4,  t); }
}

// ---------------- per-layer GEMM: A (LDS) x Wt[N][KP] bf16 (global/L2) -------------
// MT m-tiles (rows = MT*16). Wave w owns col-tiles {w + j*WS, j < NCT}.
template<int MT, int LDA, int KP, int N, int NCT, int WS, int LDO>
__device__ __forceinline__ void mlp_layer(const __bf16* __restrict__ Wt,
                                          const float* __restrict__ bias,
                                          const __bf16* Ain, __bf16* Aout,
                                          int w, int lane) {
  const int lrow = lane & 15;
  const int kg = (lane >> 4) * 8;

  f32x4 acc[NCT][MT];
  #pragma unroll
  for (int j = 0; j < NCT; ++j)
    #pragma unroll
    for (int m = 0; m < MT; ++m)
      #pragma unroll
      for (int i = 0; i < 4; ++i) acc[j][m][i] = 0.f;

  int col[NCT];
  #pragma unroll
  for (int j = 0; j < NCT; ++j) col[j] = (w + j * WS) * 16 + lrow;

  for (int k0 = 0; k0 < KP; k0 += 32) {
    bf16x8 af[MT];
    #pragma unroll
    for (int m = 0; m < MT; ++m)
      af[m] = *(const bf16x8*)(Ain + (m * 16 + lrow) * LDA + k0 + kg);
    #pragma unroll
    for (int j = 0; j < NCT; ++j) {
      bf16x8 bw = *(const bf16x8*)(Wt + (size_t)col[j] * KP + k0 + kg);
      #pragma unroll
      for (int m = 0; m < MT; ++m)
        acc[j][m] = __builtin_amdgcn_mfma_f32_16x16x32_bf16(af[m], bw, acc[j][m], 0, 0, 0);
    }
  }

  const int rbase = (lane >> 4) * 4;
  #pragma unroll
  for (int j = 0; j < NCT; ++j) {
    float bv = bias[col[j]];
    #pragma unroll
    for (int m = 0; m < MT; ++m)
      #pragma unroll
      for (int i = 0; i < 4; ++i) {
        float v = acc[j][m][i] + bv;
        v = fmaxf(v, 0.f);
        Aout[(m * 16 + rbase + i) * LDO + col[j]] = (__bf16)v;
      }
  }
}

// ---------------- fused: pipelined {gather || layer-1} + layers 2-5 + combine -------
// 64 rows/block, 1024 threads (16 waves), 1 block/CU (R5 structure).
__global__ __launch_bounds__(1024) void k_fused(
    const float* __restrict__ x_int,   // [B,13]
    const int*   __restrict__ x_cat,   // [B,26]
    const float* __restrict__ emb,     // [26,V,16]
    const float* __restrict__ lin,     // [26,V]
    const float* __restrict__ W_num,   // [13]
    const float* __restrict__ b_num,   // [1]
    const float* __restrict__ bias0,   // [1]
    const __bf16* __restrict__ Wt1, const float* __restrict__ b1,
    const __bf16* __restrict__ Wt2, const float* __restrict__ b2,
    const __bf16* __restrict__ Wt3, const float* __restrict__ b3,
    const __bf16* __restrict__ Wt4, const float* __restrict__ b4,
    const float* __restrict__ W5, const float* __restrict__ b5,
    float* __restrict__ out) {
  // LDS (125184 B): A0 @0 : 64x456 bf16; A1 @58368 : 64x520 bf16 (s_idx aliases
  // A1 head, dead before first A1 write); s_part @124928 : 64 f32.
  __shared__ __align__(16) char smem[125184];
  __bf16* A0 = (__bf16*)smem;
  __bf16* A1 = (__bf16*)(smem + 58368);
  int* s_idx = (int*)(smem + 58368);
  float* s_part = (float*)(smem + 124928);

  const int t = threadIdx.x;
  const int row0 = blockIdx.x * 64;
  const int w = t >> 6, lane = t & 63;
  const int lrow = lane & 15, kg = (lane >> 4) * 8;

  // ---- stage categorical indices ----
  for (int i = t; i < 64 * NFEAT; i += 1024) {
    int r = i / NFEAT, f = i - r * NFEAT;
    s_idx[i] = x_cat[(size_t)(row0 + r) * NFEAT + f];
  }
  __syncthreads();

  const int r = t >> 4, d = t & 15;
  const int g = d >> 2, q = d & 3;   // feature-group (mod 4), dim-quad

  // ---- linear terms (issued early, consumed after layer-1 loop) ----
  float lin_s = 0.f;
  if (d < 13) {
    lin_s = lin[(size_t)d * VOCAB + s_idx[r * NFEAT + d]]
          + lin[(size_t)(d + 13) * VOCAB + s_idx[r * NFEAT + d + 13]]
          + x_int[(size_t)(row0 + r) * 13 + d] * W_num[d];
  }
  // x_int values for chunk-6 LDS tail (cols 416..447), threads d=8..11
  float xv[4] = {0.f, 0.f, 0.f, 0.f};
  if (d >= 8 && d < 12) {
    int base = (d - 8) * 4;
    #pragma unroll
    for (int i = 0; i < 4; ++i)
      if (base + i < 13) xv[i] = x_int[(size_t)(row0 + r) * 13 + base + i];
  }

  // ---- layer-1 accumulators (NCT=2, wave-stride 16) ----
  f32x4 acc[2][4];
  #pragma unroll
  for (int j = 0; j < 2; ++j)
    #pragma unroll
    for (int m = 0; m < 4; ++m)
      #pragma unroll
      for (int i = 0; i < 4; ++i) acc[j][m][i] = 0.f;
  const int colL1[2] = { w * 16 + lrow, (w + 16) * 16 + lrow };

  // ---- pipelined gather || layer-1: 7 chunks of 64 K-cols (4 features) ----
  float fsum[4] = {0.f,0.f,0.f,0.f}, fsq[4] = {0.f,0.f,0.f,0.f};
  f32x4 cur;
  {
    int idx = s_idx[r * NFEAT + g];
    cur = *(const f32x4*)(emb + ((size_t)g * VOCAB + idx) * 16 + q * 4);
  }

  #pragma unroll
  for (int c = 0; c < 7; ++c) {
    // issue next chunk's gather (overlaps this chunk's MFMA below)
    f32x4 nxt;
    if (c < 6) {
      int fc = 4 * (c + 1) + g;
      if (fc < NFEAT) {
        int idx = s_idx[r * NFEAT + fc];
        nxt = *(const f32x4*)(emb + ((size_t)fc * VOCAB + idx) * 16 + q * 4);
      }
    }
    // consume current chunk -> LDS + FM partials
    const int colbase = c * 64 + g * 16 + q * 4;
    if (4 * c + g < NFEAT) {
      bf16x4 pk;
      #pragma unroll
      for (int i = 0; i < 4; ++i) {
        fsum[i] += cur[i]; fsq[i] += cur[i] * cur[i];
        pk[i] = (__bf16)cur[i];
      }
      *(bf16x4*)(A0 + r * 456 + colbase) = pk;
    } else {                       // c==6, g>=2: x_int + zero pad
      bf16x4 pk;
      #pragma unroll
      for (int i = 0; i < 4; ++i) pk[i] = (__bf16)xv[i];
      *(bf16x4*)(A0 + r * 456 + colbase) = pk;
    }
    bar_lgkm();   // prefetches (vmcnt) stay in flight
    // layer-1 MFMA over this chunk's 2 K-steps, Wt1 bf16 streamed from L2/L3
    #pragma unroll
    for (int ks = 0; ks < 2; ++ks) {
      const int k0 = c * 64 + ks * 32;
      bf16x8 af[4];
      #pragma unroll
      for (int m = 0; m < 4; ++m)
        af[m] = *(const bf16x8*)(A0 + (m * 16 + lrow) * 456 + k0 + kg);
      #pragma unroll
      for (int j = 0; j < 2; ++j) {
        bf16x8 bw = *(const bf16x8*)(Wt1 + (size_t)colL1[j] * 448 + k0 + kg);
        #pragma unroll
        for (int m = 0; m < 4; ++m)
          acc[j][m] = __builtin_amdgcn_mfma_f32_16x16x32_bf16(af[m], bw, acc[j][m], 0, 0, 0);
      }
    }
    cur = nxt;
  }

  // ---- layer-1 epilogue: bias + ReLU -> A1 (overwrites s_idx alias: safe now) ----
  {
    const int rbase = (lane >> 4) * 4;
    #pragma unroll
    for (int j = 0; j < 2; ++j) {
      float bv = b1[colL1[j]];
      #pragma unroll
      for (int m = 0; m < 4; ++m)
        #pragma unroll
        for (int i = 0; i < 4; ++i) {
          float v = acc[j][m][i] + bv;
          v = fmaxf(v, 0.f);
          A1[(m * 16 + rbase + i) * 520 + colL1[j]] = (__bf16)v;
        }
    }
  }

  // ---- FM + linear combine -> s_part ----
  {
    #pragma unroll
    for (int i = 0; i < 4; ++i) {
      fsum[i] += __shfl_xor(fsum[i], 4); fsq[i] += __shfl_xor(fsq[i], 4);
      fsum[i] += __shfl_xor(fsum[i], 8); fsq[i] += __shfl_xor(fsq[i], 8);
    }
    float fmq = 0.f;
    #pragma unroll
    for (int i = 0; i < 4; ++i) fmq += fsum[i] * fsum[i] - fsq[i];
    fmq += __shfl_xor(fmq, 1);
    fmq += __shfl_xor(fmq, 2);     // full FM, replicated over d
    float linred = lin_s;
    #pragma unroll
    for (int off = 1; off < 16; off <<= 1) linred += __shfl_xor(linred, off, 16);
    if (d == 0) s_part[r] = 0.5f * fmq + linred + bias0[0] + b_num[0];
  }
  __syncthreads();

  // ---- layers 2-4 (bf16 weights, one dwordx4 per fragment) ----
  mlp_layer<4, 520, 512, 256, 1, 16, 264>(Wt2, b2, A1, A0, w, lane);
  __syncthreads();
  if (w < 8) mlp_layer<4, 264, 256, 128, 1, 8, 136>(Wt3, b3, A0, A1, w, lane);
  __syncthreads();
  if (w < 4) mlp_layer<4, 136, 128, 64, 1, 4, 72>(Wt4, b4, A1, A0, w, lane);
  __syncthreads();

  // ---- final 64->1 dot + combine ----
  {
    const int rr = t >> 4, gg = t & 15;
    float s = 0.f;
    #pragma unroll
    for (int i = 0; i < 4; ++i)
      s += (float)A0[rr * 72 + gg * 4 + i] * W5[gg * 4 + i];
    #pragma unroll
    for (int off = 1; off < 16; off <<= 1) s += __shfl_xor(s, off, 16);
    if (gg == 0) out[row0 + rr] = s + b5[0] + s_part[rr];
  }
}

extern "C" void kernel_launch(void* const* d_in, const int* in_sizes, int n_in,
                              void* d_out, int out_size, void* d_ws, size_t ws_size,
                              hipStream_t stream) {
  const float* x_int = (const float*)d_in[0];
  const int*   x_cat = (const int*)d_in[1];
  const float* emb   = (const float*)d_in[2];
  const float* lin   = (const float*)d_in[3];
  const float* W_num = (const float*)d_in[4];
  const float* b_num = (const float*)d_in[5];
  const float* bias  = (const float*)d_in[6];
  const float* W1 = (const float*)d_in[7];  const float* b1 = (const float*)d_in[8];
  const float* W2 = (const float*)d_in[9];  const float* b2 = (const float*)d_in[10];
  const float* W3 = (const float*)d_in[11]; const float* b3 = (const float*)d_in[12];
  const float* W4 = (const float*)d_in[13]; const float* b4 = (const float*)d_in[14];
  const float* W5 = (const float*)d_in[15]; const float* b5 = (const float*)d_in[16];
  float* out = (float*)d_out;

  char* ws = (char*)d_ws;
  __bf16* Wt1 = (__bf16*)(ws);            // [512][448] = 458752 B
  __bf16* Wt2 = (__bf16*)(ws + 458752);   // [256][512] = 262144 B
  __bf16* Wt3 = (__bf16*)(ws + 720896);   // [128][256] =  65536 B
  __bf16* Wt4 = (__bf16*)(ws + 786432);   // [64][128]  =  16384 B

  k_convAll<<<392, 256, 0, stream>>>(W1, W2, W3, W4, Wt1, Wt2, Wt3, Wt4);

  k_fused<<<NROWS / 64, 1024, 0, stream>>>(x_int, x_cat, emb, lin, W_num, b_num, bias,
                                           Wt1, b1, Wt2, b2, Wt3, b3, Wt4, b4, W5, b5,
                                           out);
}